// Round 5
// baseline (133.228 us; speedup 1.0000x reference)
//
#include <hip/hip_runtime.h>
#include <hip/hip_bf16.h>

// MixedScoresSDPA: out = softmax(MLP2(relu(MLP1([QK^T*scale, dmat])))) @ V
// B=8 H=8 M=N=512 D=64 HID=16, fp32 in/out.
// r5: double-buffered DMA staging (tile t+1 in flight during tile t compute),
//     dmat register-prefetch one tile ahead, single barrier per tile.
//     Prep kernel (unchanged): pre-swizzled bf16 hi/lo K and V^T tile images.

typedef __attribute__((ext_vector_type(4))) float f32x4;
typedef __attribute__((ext_vector_type(8))) __bf16 bf16x8;
typedef __attribute__((ext_vector_type(4))) __bf16 bf16x4;

static __device__ __forceinline__ float rlf(float x) {   // force SGPR residency
    return __uint_as_float(__builtin_amdgcn_readfirstlane(__float_as_uint(x)));
}
static __device__ __forceinline__ void cvt2(float x, __bf16& h, __bf16& l) {
    h = (__bf16)x;                    // RNE f32->bf16
    l = (__bf16)(x - (float)h);       // residual
}
// XOR-swizzled index for [64][64] bf16 tiles: chunk-of-8 ^ (row&7) -> conflict-free b128.
static __device__ __forceinline__ int sw64(int row, int col) {
    return row * 64 + ((((col >> 3) ^ (row & 7)) << 3) | (col & 7));
}
// async global->LDS, 16B per lane (dest = wave-uniform base + lane*16; our mapping is lane-linear)
static __device__ __forceinline__ void dma16(const __bf16* g, __bf16* l) {
    __builtin_amdgcn_global_load_lds(
        (const __attribute__((address_space(1))) unsigned*)g,
        (__attribute__((address_space(3))) unsigned*)l, 16, 0, 0);
}

#define B_ 8
#define H_ 8
#define M_ 512
#define N_ 512
#define D_ 64
#define HID_ 16

// ---------------- prep: K -> (KH,KL) sw64 images; V -> (VTH,VTL) transposed sw64 images.
// ws layout per (bh,nt) [512 tiles]: 16384 bf16 = {KH,KL,VTH,VTL} x 4096 elems.
__global__ __launch_bounds__(256) void prep_kernel(
    const float* __restrict__ kg, const float* __restrict__ vg,
    __bf16* __restrict__ ws)
{
    __shared__ float vld[64 * 68];   // V tile f32, padded stride 68
    const int t   = threadIdx.x;
    const int blk = blockIdx.x;                   // bh*8 + nt
    const long base = (long)blk * 4096;           // element offset of this 64x64 tile
    __bf16* out = ws + (long)blk * 16384;

    // stage V tile into LDS (row-major, padded)
#pragma unroll
    for (int it = 0; it < 4; ++it) {
        const int e = it * 1024 + t * 4;
        const int rr = e >> 6, c0 = e & 63;
        f32x4 v4 = *(const f32x4*)(vg + base + e);
        *(f32x4*)(vld + rr * 68 + c0) = v4;
    }

    // K images (straight from global; row-major with chunk pre-swizzle)
#pragma unroll
    for (int qq = t; qq < 512; qq += 256) {
        const int row = qq >> 3, c = qq & 7;
        const float* src = kg + base + row * 64 + ((c ^ (row & 7)) << 3);
        f32x4 a = *(const f32x4*)src;
        f32x4 b4 = *(const f32x4*)(src + 4);
        bf16x8 hv, lv;
#pragma unroll
        for (int j = 0; j < 4; ++j) {
            __bf16 h, l;
            cvt2(a[j], h, l);  hv[j] = h;     lv[j] = l;
            cvt2(b4[j], h, l); hv[4 + j] = h; lv[4 + j] = l;
        }
        *(bf16x8*)(out + qq * 8) = hv;            // KH
        *(bf16x8*)(out + 4096 + qq * 8) = lv;     // KL
    }
    __syncthreads();

    // V^T images: image(d, c*8+j) = V[((c^(d&7))*8+j)][d]
#pragma unroll
    for (int qq = t; qq < 512; qq += 256) {
        const int d = qq & 63, c = qq >> 6;       // d-major across lanes: conflict-free
        bf16x8 hv, lv;
#pragma unroll
        for (int j = 0; j < 8; ++j) {
            const int n = ((c ^ (d & 7)) << 3) + j;
            __bf16 h, l;
            cvt2(vld[n * 68 + d], h, l);
            hv[j] = h; lv[j] = l;
        }
        const int pos = d * 64 + c * 8;
        *(bf16x8*)(out + 8192 + pos) = hv;        // VTH
        *(bf16x8*)(out + 12288 + pos) = lv;       // VTL
    }
}

// ---------------- main kernel
__global__ __launch_bounds__(256, 2) void msdpa_kernel(
    const float* __restrict__ qg, const __bf16* __restrict__ ws,
    const float* __restrict__ dg, const float* __restrict__ w1g,
    const float* __restrict__ b1g, const float* __restrict__ w2g,
    float* __restrict__ outg)
{
    extern __shared__ __bf16 smem[];
    // buf0 @0 (16384 elems), buf1 @16384; each: KH 0, KL 4096, VTH 8192, VTL 12288.
    // P @32768: PH +wv*1024, PL @36864 +wv*1024.  Total 81920 B.

    const int tid  = threadIdx.x;
    const int lane = tid & 63;
    const int wv   = tid >> 6;
    const int r16  = lane & 15;
    const int g    = lane >> 4;

    const int bm = blockIdx.x;
    const int h  = blockIdx.y;
    const int b  = blockIdx.z;

    __bf16* PHw = smem + 32768 + wv * 1024;   // [16][64] chunk-swizzled
    __bf16* PLw = smem + 36864 + wv * 1024;

    const long bh = (long)(b * H_ + h);
    const __bf16* wsbh = ws + bh * (8L * 16384);
    const float* dmp = dg + ((long)b * M_ + (long)bm * 64 + wv * 16 + r16) * N_ + g * 4;

    __bf16* bcur = smem;
    __bf16* bnxt = smem + 16384;

    // ---- issue tile-0 DMA first; overlap with constant/Q setup below
#pragma unroll
    for (int i = 0; i < 8; ++i)
        dma16(wsbh + i * 2048 + tid * 8, bcur + i * 2048 + tid * 8);

    // per-head MLP constants -> SGPRs. scale 1/8 folded into af, log2e*0.5 into wa;
    // b2 dropped (softmax shift-invariant). relu(u) = (u+|u|)/2 ->
    // mixed*log2e = (A*s + C*d + B0) + sum_f wa_f * |u_f|
    const float* w1h = w1g + h * 2 * HID_;
    const float* b1h = b1g + h * HID_;
    const float* w2h = w2g + h * HID_;
    float af[HID_], cf[HID_], bf_[HID_], wa[HID_];
    float A = 0.f, C = 0.f, B0 = 0.f;
#pragma unroll
    for (int f = 0; f < HID_; ++f) {
        af[f] = rlf(w1h[f]) * 0.125f;
        cf[f] = rlf(w1h[HID_ + f]);
        bf_[f] = rlf(b1h[f]);
        wa[f] = rlf(w2h[f]) * (1.4426950408889634f * 0.5f);
        A  = fmaf(wa[f], af[f], A);
        C  = fmaf(wa[f], cf[f], C);
        B0 = fmaf(wa[f], bf_[f], B0);
    }

    // Q fragments (hi/lo bf16), B-operand: lane holds Q[m=r16][d = ks*32 + g*8 + j]
    const float* qbase = qg + (bh * M_ + (long)bm * 64 + wv * 16 + r16) * D_;
    bf16x8 qh[2], ql[2];
#pragma unroll
    for (int ks = 0; ks < 2; ++ks) {
        f32x4 x0 = *(const f32x4*)(qbase + ks * 32 + g * 8);
        f32x4 x1 = *(const f32x4*)(qbase + ks * 32 + g * 8 + 4);
        bf16x8 hv, lv;
#pragma unroll
        for (int j = 0; j < 4; ++j) {
            __bf16 h_, l_;
            cvt2(x0[j], h_, l_); hv[j] = h_; lv[j] = l_;
            cvt2(x1[j], h_, l_); hv[4 + j] = h_; lv[4 + j] = l_;
        }
        qh[ks] = hv; ql[ks] = lv;
    }

    // dmat tile-0 prefetch into registers
    f32x4 dmvc[4], dmvn[4];
#pragma unroll
    for (int n16 = 0; n16 < 4; ++n16)
        dmvc[n16] = *(const f32x4*)(dmp + n16 * 16);

    f32x4 oacc[4];
#pragma unroll
    for (int dt = 0; dt < 4; ++dt) oacc[dt] = f32x4{0.f, 0.f, 0.f, 0.f};
    float mrun = -1e30f, lsum = 0.0f;

    __syncthreads();   // vmcnt(0): tile-0 staged (setup above overlapped the DMA)

    for (int nt = 0; nt < 8; ++nt) {
        // ---- issue next tile's DMA + dmat prefetch (in flight through this
        //      whole tile's compute; drained at the closing barrier)
        if (nt < 7) {
            const __bf16* tile = wsbh + (nt + 1) * 16384;
#pragma unroll
            for (int i = 0; i < 8; ++i)
                dma16(tile + i * 2048 + tid * 8, bnxt + i * 2048 + tid * 8);
#pragma unroll
            for (int n16 = 0; n16 < 4; ++n16)
                dmvn[n16] = *(const f32x4*)(dmp + (nt + 1) * 64 + n16 * 16);
        }

        __bf16* KH  = bcur;
        __bf16* KL  = bcur + 4096;
        __bf16* VTH = bcur + 8192;
        __bf16* VTL = bcur + 12288;

        // ---- QK^T (swapped: A=K, B=Q) -> S^T; 3-term hi/lo split
        f32x4 sacc[4];
#pragma unroll
        for (int n16 = 0; n16 < 4; ++n16) sacc[n16] = f32x4{0.f, 0.f, 0.f, 0.f};
#pragma unroll
        for (int n16 = 0; n16 < 4; ++n16) {
            const int row = n16 * 16 + r16;
#pragma unroll
            for (int ks = 0; ks < 2; ++ks) {
                const int off = sw64(row, ks * 32 + g * 8);
                bf16x8 kh_ = *(const bf16x8*)(KH + off);
                bf16x8 kl_ = *(const bf16x8*)(KL + off);
                sacc[n16] = __builtin_amdgcn_mfma_f32_16x16x32_bf16(kh_, qh[ks], sacc[n16], 0, 0, 0);
                sacc[n16] = __builtin_amdgcn_mfma_f32_16x16x32_bf16(kh_, ql[ks], sacc[n16], 0, 0, 0);
                sacc[n16] = __builtin_amdgcn_mfma_f32_16x16x32_bf16(kl_, qh[ks], sacc[n16], 0, 0, 0);
            }
        }
        // lane holds S^T: m = r16, n = 16*n16 + 4*g + r

        // ---- MLP via relu->abs: ms = A*s + C*d + B0 + sum_f wa_f*|af_f*s + cf_f*d + bf_f|
        float ms[4][4];
#pragma unroll
        for (int n16 = 0; n16 < 4; ++n16)
#pragma unroll
            for (int r = 0; r < 4; ++r) {
                const float s = sacc[n16][r], d = dmvc[n16][r];
                float acc = fmaf(A, s, fmaf(C, d, B0));
#pragma unroll
                for (int f = 0; f < HID_; ++f) {
                    const float u = fmaf(af[f], s, fmaf(cf[f], d, bf_[f]));
                    acc = fmaf(wa[f], fabsf(u), acc);   // |u| via VOP3 abs modifier
                }
                ms[n16][r] = acc;
            }

        // ---- online softmax (rows lane-local; reduce across 4 lane-groups)
        float mloc = -1e30f;
#pragma unroll
        for (int n16 = 0; n16 < 4; ++n16)
#pragma unroll
            for (int r = 0; r < 4; ++r) mloc = fmaxf(mloc, ms[n16][r]);
        mloc = fmaxf(mloc, __shfl_xor(mloc, 16));
        mloc = fmaxf(mloc, __shfl_xor(mloc, 32));
        const float mnew = fmaxf(mrun, mloc);
        const float sc = exp2f(mrun - mnew);
        mrun = mnew;

        float psum = 0.0f;
#pragma unroll
        for (int n16 = 0; n16 < 4; ++n16) {
            bf16x4 ph4, pl4;
#pragma unroll
            for (int r = 0; r < 4; ++r) {
                const float p = exp2f(ms[n16][r] - mnew);
                psum += p;
                __bf16 h_, l_;
                cvt2(p, h_, l_);
                ph4[r] = h_; pl4[r] = l_;
            }
            // 8-elem chunk cc stored at chunk cc^(r16&7); this 4-group is half (g&1)
            const int cc = 2 * n16 + (g >> 1);
            const int pos = r16 * 64 + (((cc ^ (r16 & 7)) << 3) | ((g & 1) << 2));
            *(bf16x4*)(PHw + pos) = ph4;
            *(bf16x4*)(PLw + pos) = pl4;
        }
        lsum = lsum * sc + psum;

        // ---- rescale O (O rows are m=4g+r; scale lives at lane m)
        float scm[4];
#pragma unroll
        for (int r = 0; r < 4; ++r) scm[r] = __shfl(sc, g * 4 + r);
#pragma unroll
        for (int dt = 0; dt < 4; ++dt)
#pragma unroll
            for (int r = 0; r < 4; ++r) oacc[dt][r] *= scm[r];

        // ---- PV: A=P (b128, chunk ks*4+g), B=V^T (b128 sw64); 3-term hi/lo split
#pragma unroll
        for (int ks = 0; ks < 2; ++ks) {
            const int pofs = r16 * 64 + ((((ks * 4 + g)) ^ (r16 & 7)) << 3);
            bf16x8 pa = *(const bf16x8*)(PHw + pofs);
            bf16x8 pb = *(const bf16x8*)(PLw + pofs);
#pragma unroll
            for (int dt = 0; dt < 4; ++dt) {
                const int vofs = sw64(dt * 16 + r16, ks * 32 + g * 8);
                bf16x8 vh = *(const bf16x8*)(VTH + vofs);
                bf16x8 vl = *(const bf16x8*)(VTL + vofs);
                oacc[dt] = __builtin_amdgcn_mfma_f32_16x16x32_bf16(pa, vh, oacc[dt], 0, 0, 0);
                oacc[dt] = __builtin_amdgcn_mfma_f32_16x16x32_bf16(pa, vl, oacc[dt], 0, 0, 0);
                oacc[dt] = __builtin_amdgcn_mfma_f32_16x16x32_bf16(pb, vh, oacc[dt], 0, 0, 0);
            }
        }

        // ---- close tile: drain next-tile DMA (overlapped above), swap buffers
        if (nt < 7) {
            __syncthreads();   // emits s_waitcnt vmcnt(0) lgkmcnt(0); s_barrier
            __bf16* tmp = bcur; bcur = bnxt; bnxt = tmp;
#pragma unroll
            for (int n16 = 0; n16 < 4; ++n16) dmvc[n16] = dmvn[n16];
        }
    }

    // ---- epilogue
    lsum += __shfl_xor(lsum, 16);
    lsum += __shfl_xor(lsum, 32);
    float linv[4];
#pragma unroll
    for (int r = 0; r < 4; ++r) linv[r] = 1.0f / __shfl(lsum, g * 4 + r);

    float* obase = outg + (bh * M_ + (long)bm * 64 + wv * 16) * D_;
#pragma unroll
    for (int dt = 0; dt < 4; ++dt)
#pragma unroll
        for (int r = 0; r < 4; ++r)
            obase[(g * 4 + r) * D_ + dt * 16 + r16] = oacc[dt][r] * linv[r];
}

extern "C" void kernel_launch(void* const* d_in, const int* in_sizes, int n_in,
                              void* d_out, int out_size, void* d_ws, size_t ws_size,
                              hipStream_t stream) {
    const float* q  = (const float*)d_in[0];
    const float* k  = (const float*)d_in[1];
    const float* v  = (const float*)d_in[2];
    const float* dm = (const float*)d_in[3];
    const float* w1 = (const float*)d_in[4];
    const float* b1 = (const float*)d_in[5];
    const float* w2 = (const float*)d_in[6];
    // d_in[7] = mix_b2: unused (softmax shift-invariant)
    float* out = (float*)d_out;
    __bf16* ws = (__bf16*)d_ws;   // needs 512*16384*2B = 16.8 MB

    prep_kernel<<<dim3(512), dim3(256), 0, stream>>>(k, v, ws);

    (void)hipFuncSetAttribute(reinterpret_cast<const void*>(msdpa_kernel),
                              hipFuncAttributeMaxDynamicSharedMemorySize, 81920);
    dim3 grid(M_ / 64, H_, B_);   // 512 blocks = 2/CU; LDS 80KB x2 = 160KB/CU exactly
    msdpa_kernel<<<grid, dim3(256), 81920, stream>>>(q, ws, dm, w1, b1, w2, out);
}